// Round 3
// baseline (5877.917 us; speedup 1.0000x reference)
//
#include <hip/hip_runtime.h>

// B=8, T=1024, E=768, H=12.
// Round 7b: pre-split fp32 -> (hi,lo) bf16 ONCE (x, W, WO; Q/K/V/S/Z written
// as hi/lo pairs by producer epilogues / softmax). All GEMMs are pure-bf16
// split-product (Ah*Bh + Al*Bh + Ah*Bl) with global_load_lds width-16
// staging into linear LDS, source-pre-swizzled (slot ^= (row>>1)&3) so
// ds_read_b128 fragment reads are bank-even. No VALU conversion in hot loop.

typedef __bf16 bf16x8 __attribute__((ext_vector_type(8)));
typedef float  f32x4  __attribute__((ext_vector_type(4)));
typedef unsigned short u16;
typedef u16 u16x8 __attribute__((ext_vector_type(8)));
typedef unsigned int u32;

__device__ __forceinline__ float bf2f(u16 u) {
    union { u32 i; float f; } x; x.i = ((u32)u) << 16; return x.f;
}
__device__ __forceinline__ u16 f2bf(float f) {
    __bf16 h = (__bf16)f; union { __bf16 b; u16 u; } x; x.b = h; return x.u;
}
__device__ __forceinline__ void split2(float v, u16& h, u16& l) {
    h = f2bf(v); l = f2bf(v - bf2f(h));
}

__device__ __forceinline__ void gl16(const void* g, void* l) {
    __builtin_amdgcn_global_load_lds(
        (const __attribute__((address_space(1))) u32*)g,
        (__attribute__((address_space(3))) u32*)l, 16, 0, 0);
}

// ---------------- 128x128 split-bf16 core ----------------
// A: hi/lo row-major (M x K, lda).  B: BKMAJ=0 -> B^T hi/lo row-major
// (N x K, ldb) staged via global_load_lds; BKMAJ=1 -> B hi/lo k-major
// (K x N, ldb) staged via coalesced bf16 loads + swizzled ds_write_b128.
// WIN=1: per-lane A-source clamp to zero page for the quirky flat window.
template<int BKMAJ, int WIN>
__device__ __forceinline__ void core(
    const u16* __restrict__ Ah, const u16* __restrict__ Al,
    const u16* __restrict__ Bh, const u16* __restrict__ Bl,
    float* __restrict__ C, u16* __restrict__ Ch, u16* __restrict__ Cl,
    int K, int lda, int ldb, int ldc,
    long long aShift, long long aHi, const u16* __restrict__ zp,
    int mClip, int mode, int mtile, int kChunk, int kChunks, int n0)
{
    __shared__ u16 Ahs[4096], Als[4096], Bhs[4096], Bls[4096]; // 32 KiB

    const int tid = threadIdx.x, lane = tid & 63, w = tid >> 6;
    const int m0 = mtile * 128;
    const int wm = (w & 1) << 6, wn = (w >> 1) << 6;
    const int lr = lane & 15, lq = lane >> 4;
    const int rs = (lr >> 1) & 3;
    const int fro = (lq ^ rs) << 4;            // frag byte offset in row

    // DMA staging geometry: wave w covers LDS rows w*16..+15 (call 0)
    // and +64 (call 1); lane -> (row, 16B slot). Source k pre-swizzled.
    const int srow = (w << 4) + (lane >> 2);
    const int kk = (((lane & 3) ^ ((srow >> 1) & 3)) << 3);
    const int lds0 = (w << 10), lds1 = lds0 + 4096;

    // k-major B staging (scores / Z)
    const int nB = tid & 127, khB = (tid >> 7) << 4;
    const int rsB = (nB >> 1) & 3;
    const int sB0 = (((khB >> 3) ^ rsB) << 4);
    const int sB1 = ((((khB >> 3) | 1) ^ rsB) << 4);

    f32x4 acc[4][4] = {};
    const int kLen = K / kChunks;
    const int kBeg = kChunk * kLen, kEnd = kBeg + kLen;

    u16 rBh[16], rBl[16];
    auto loadB = [&](int k0) {
        if constexpr (BKMAJ) {
#pragma unroll
            for (int j = 0; j < 16; ++j) {
                long long o = (long long)(k0 + khB + j) * ldb + n0 + nB;
                rBh[j] = Bh[o]; rBl[j] = Bl[o];
            }
        }
    };
    auto stage = [&](int k0) {
        long long o1 = (long long)(m0 + srow) * lda + k0 + kk;
        long long o2 = o1 + (long long)64 * lda;
        const u16 *p1h = Ah + o1, *p1l = Al + o1;
        const u16 *p2h = Ah + o2, *p2l = Al + o2;
        if constexpr (WIN) {
            long long a1 = o1 + aShift, a2 = o2 + aShift;
            bool v1 = (a1 >= 0) && (a1 < aHi);
            bool v2 = (a2 >= 0) && (a2 < aHi);
            p1h = v1 ? Ah + a1 : zp;  p1l = v1 ? Al + a1 : zp;
            p2h = v2 ? Ah + a2 : zp;  p2l = v2 ? Al + a2 : zp;
        }
        gl16(p1h, (char*)Ahs + lds0);  gl16(p2h, (char*)Ahs + lds1);
        gl16(p1l, (char*)Als + lds0);  gl16(p2l, (char*)Als + lds1);
        if constexpr (!BKMAJ) {
            long long b1 = (long long)(n0 + srow) * ldb + k0 + kk;
            long long b2 = b1 + (long long)64 * ldb;
            gl16(Bh + b1, (char*)Bhs + lds0);  gl16(Bh + b2, (char*)Bhs + lds1);
            gl16(Bl + b1, (char*)Bls + lds0);  gl16(Bl + b2, (char*)Bls + lds1);
        }
    };
    auto writeB = [&]() {
        if constexpr (BKMAJ) {
            u16x8 h0, h1, l0, l1;
#pragma unroll
            for (int j = 0; j < 8; ++j) {
                h0[j] = rBh[j]; h1[j] = rBh[j + 8];
                l0[j] = rBl[j]; l1[j] = rBl[j + 8];
            }
            *(u16x8*)((char*)Bhs + nB * 64 + sB0) = h0;
            *(u16x8*)((char*)Bhs + nB * 64 + sB1) = h1;
            *(u16x8*)((char*)Bls + nB * 64 + sB0) = l0;
            *(u16x8*)((char*)Bls + nB * 64 + sB1) = l1;
        }
    };

    loadB(kBeg);
    for (int k0 = kBeg; k0 < kEnd; k0 += 32) {
        stage(k0);                       // async DMA into LDS
        writeB();                        // (BKMAJ) prefetched B -> LDS
        __syncthreads();                 // drains vmcnt + lgkmcnt
        if (k0 + 32 < kEnd) loadB(k0 + 32);   // (BKMAJ) prefetch next

        bf16x8 a_h[4], a_l[4];
#pragma unroll
        for (int mi = 0; mi < 4; ++mi) {
            int off = ((wm + (mi << 4) + lr) << 6) + fro;
            a_h[mi] = *(const bf16x8*)((char*)Ahs + off);
            a_l[mi] = *(const bf16x8*)((char*)Als + off);
        }
#pragma unroll
        for (int ni = 0; ni < 4; ++ni) {
            int off = ((wn + (ni << 4) + lr) << 6) + fro;
            bf16x8 b_h = *(const bf16x8*)((char*)Bhs + off);
            bf16x8 b_l = *(const bf16x8*)((char*)Bls + off);
#pragma unroll
            for (int mi = 0; mi < 4; ++mi) {
                acc[mi][ni] = __builtin_amdgcn_mfma_f32_16x16x32_bf16(a_h[mi], b_h, acc[mi][ni], 0, 0, 0);
                acc[mi][ni] = __builtin_amdgcn_mfma_f32_16x16x32_bf16(a_l[mi], b_h, acc[mi][ni], 0, 0, 0);
                acc[mi][ni] = __builtin_amdgcn_mfma_f32_16x16x32_bf16(a_h[mi], b_l, acc[mi][ni], 0, 0, 0);
            }
        }
        __syncthreads();
    }

    // Epilogue: C/D layout col = lane&15, row = (lane>>4)*4 + reg  [m89]
#pragma unroll
    for (int mi = 0; mi < 4; ++mi)
#pragma unroll
        for (int r = 0; r < 4; ++r) {
            int row = m0 + wm + (mi << 4) + (lq << 2) + r;
            if (row < mClip) {
#pragma unroll
                for (int ni = 0; ni < 4; ++ni) {
                    long long off = (long long)row * ldc + n0 + wn + (ni << 4) + lr;
                    float v = acc[mi][ni][r];
                    if (mode == 2)      atomicAdd(&C[off], v);
                    else if (mode == 1) { u16 hh, ll; split2(v, hh, ll); Ch[off] = hh; Cl[off] = ll; }
                    else                C[off] = v;
                }
            }
        }
}

// Fused QKV: grid (6, nbT/128, 3); z selects W-slice and output pair.
__global__ __launch_bounds__(256, 3)
void g_qkv(const u16* __restrict__ Xh, const u16* __restrict__ Xl,
           const u16* __restrict__ Wth, const u16* __restrict__ Wtl,
           u16* __restrict__ Qh, u16* __restrict__ Ql,
           u16* __restrict__ Kh, u16* __restrict__ Kl,
           u16* __restrict__ Vh, u16* __restrict__ Vl)
{
    const long long EE = 768LL * 768;
    int z = blockIdx.z;
    const u16* bh = Wth + (long long)z * EE;
    const u16* bl = Wtl + (long long)z * EE;
    u16* ch = (z == 0) ? Qh : (z == 1) ? Kh : Vh;
    u16* cl = (z == 0) ? Ql : (z == 1) ? Kl : Vl;
    core<0, 0>(Xh, Xl, bh, bl, nullptr, ch, cl, 768, 768, 768, 768,
               0, 0, nullptr, 1 << 30, 1, blockIdx.y, 0, 1, blockIdx.x * 128);
}

// k-major-B GEMM (scores: B = K-flat reinterpreted (768,1024); Z: B = V).
__global__ __launch_bounds__(256, 3)
void g_km(const u16* __restrict__ Ah, const u16* __restrict__ Al,
          const u16* __restrict__ Bh, const u16* __restrict__ Bl,
          u16* __restrict__ Ch, u16* __restrict__ Cl,
          int K, int lda, int ldb, int ldc,
          long long sA, long long sB, long long sC)
{
    long long z = blockIdx.z;
    core<1, 0>(Ah + z * sA, Al + z * sA, Bh + z * sB, Bl + z * sB,
               nullptr, Ch + z * sC, Cl + z * sC,
               K, lda, ldb, ldc, 0, 0, nullptr, 1 << 30, 1,
               blockIdx.y, 0, 1, blockIdx.x * 128);
}

// Final projection: windowed A (quirky flat reshape), k-split + atomics.
__global__ __launch_bounds__(256, 3)
void g_fin(const u16* __restrict__ Zh, const u16* __restrict__ Zl,
           const u16* __restrict__ WOth, const u16* __restrict__ WOtl,
           float* __restrict__ C, const u16* __restrict__ zp,
           long long aShift, int mClip, int kChunks)
{
    const long long TE_ = 786432;
    long long z = blockIdx.z;
    core<0, 1>(Zh + z * TE_, Zl + z * TE_, WOth, WOtl, C + z * TE_,
               nullptr, nullptr, 9216, 9216, 9216, 768,
               aShift, TE_, zp, mClip, 2, 0, blockIdx.y, kChunks, blockIdx.x * 128);
}

// fp32 -> (hi,lo) bf16, flat.
__global__ void k_split(const float* __restrict__ s, u16* __restrict__ h,
                        u16* __restrict__ l, long long n)
{
    typedef u16 u16x4 __attribute__((ext_vector_type(4)));
    long long i = ((long long)blockIdx.x * blockDim.x + threadIdx.x) * 4;
    long long stride = (long long)gridDim.x * blockDim.x * 4;
    for (; i < n; i += stride) {
        float4 v = *(const float4*)(s + i);
        u16x4 hh, ll;
        u16 h0, l0, h1, l1, h2, l2, h3, l3;
        split2(v.x, h0, l0); split2(v.y, h1, l1);
        split2(v.z, h2, l2); split2(v.w, h3, l3);
        hh[0] = h0; hh[1] = h1; hh[2] = h2; hh[3] = h3;
        ll[0] = l0; ll[1] = l1; ll[2] = l2; ll[3] = l3;
        *(u16x4*)(h + i) = hh;
        *(u16x4*)(l + i) = ll;
    }
}

// fp32 (Ks x Ns) -> transposed (Ns x Ks) hi/lo bf16.
__global__ void k_tsplit(const float* __restrict__ s, u16* __restrict__ dh,
                         u16* __restrict__ dl, int Ks, int Ns)
{
    __shared__ float t[32][33];
    int tx = threadIdx.x & 31, ty = threadIdx.x >> 5;
    int kb = blockIdx.y << 5, nb_ = blockIdx.x << 5;
#pragma unroll
    for (int i = 0; i < 4; ++i)
        t[ty + 8 * i][tx] = s[(long long)(kb + ty + 8 * i) * Ns + nb_ + tx];
    __syncthreads();
#pragma unroll
    for (int i = 0; i < 4; ++i) {
        float v = t[tx][ty + 8 * i];
        long long o = (long long)(nb_ + ty + 8 * i) * Ks + kb + tx;
        u16 hh, ll; split2(v, hh, ll);
        dh[o] = hh; dl[o] = ll;
    }
}

// Per-head W transpose-split: z selects WQ/WK/WV slice; dst += z*E*E.
__global__ void k_tsplit3(const float* __restrict__ s0, const float* __restrict__ s1,
                          const float* __restrict__ s2,
                          u16* __restrict__ dh, u16* __restrict__ dl)
{
    const int E = 768; const long long EE = (long long)E * E;
    const float* s = (blockIdx.z == 0) ? s0 : (blockIdx.z == 1) ? s1 : s2;
    u16* h = dh + blockIdx.z * EE;
    u16* l = dl + blockIdx.z * EE;
    __shared__ float t[32][33];
    int tx = threadIdx.x & 31, ty = threadIdx.x >> 5;
    int kb = blockIdx.y << 5, nb_ = blockIdx.x << 5;
#pragma unroll
    for (int i = 0; i < 4; ++i)
        t[ty + 8 * i][tx] = s[(long long)(kb + ty + 8 * i) * E + nb_ + tx];
    __syncthreads();
#pragma unroll
    for (int i = 0; i < 4; ++i) {
        float v = t[tx][ty + 8 * i];
        long long o = (long long)(nb_ + ty + 8 * i) * E + kb + tx;
        u16 hh, ll; split2(v, hh, ll);
        h[o] = hh; l[o] = ll;
    }
}

// Column softmax over query axis on hi/lo bf16 pairs, in place.
__global__ __launch_bounds__(256)
void col_softmax(u16* __restrict__ Sh, u16* __restrict__ Sl, int T, float scale)
{
    const int tid = threadIdx.x, jl = tid & 63, seg = tid >> 6;
    const int j = blockIdx.x * 64 + jl;
    long long base = (long long)blockIdx.y * T * T;
    u16* sh = Sh + base; u16* sl = Sl + base;
    const int rps = T >> 2, r0 = seg * rps;

    float m = -3.4e38f, s = 0.f;
    for (int r = 0; r < rps; ++r) {
        long long o = (long long)(r0 + r) * T + j;
        float v = (bf2f(sh[o]) + bf2f(sl[o])) * scale;
        float mn = fmaxf(m, v);
        s = s * __expf(m - mn) + __expf(v - mn);
        m = mn;
    }
    __shared__ float sm[4][64], ss[4][64];
    sm[seg][jl] = m; ss[seg][jl] = s;
    __syncthreads();
    float mt = -3.4e38f, st = 0.f;
#pragma unroll
    for (int q = 0; q < 4; ++q) {
        float mq = sm[q][jl], sq = ss[q][jl];
        float mn = fmaxf(mt, mq);
        st = st * __expf(mt - mn) + sq * __expf(mq - mn);
        mt = mn;
    }
    const float inv = 1.f / st;
    for (int r = 0; r < rps; ++r) {
        long long o = (long long)(r0 + r) * T + j;
        float v = (bf2f(sh[o]) + bf2f(sl[o])) * scale;
        float p = __expf(v - mt) * inv;
        u16 hh, ll; split2(p, hh, ll);
        sh[o] = hh; sl[o] = ll;
    }
}

extern "C" void kernel_launch(void* const* d_in, const int* in_sizes, int n_in,
                              void* d_out, int out_size, void* d_ws, size_t ws_size,
                              hipStream_t stream)
{
    const float* x  = (const float*)d_in[0];   // (B,T,E)
    const float* WQ = (const float*)d_in[1];   // (H,E,E)
    const float* WK = (const float*)d_in[2];
    const float* WV = (const float*)d_in[3];
    const float* WO = (const float*)d_in[4];   // (H*E, E)
    float* out = (float*)d_out;                // (B,T,E)

    const int B = 8, T = 1024, E = 768, H = 12;
    const long long TE = (long long)T * E;     // 786432
    const long long TT = (long long)T * T;     // 1048576
    const long long HE = (long long)H * E;     // 9216
    const long long EE = (long long)E * E;

    // ---- workspace layout (bytes) ----
    char* p = (char*)d_ws;
    u16* Xh   = (u16*)p; p += (size_t)B * TE * 2;   // 12.6 MB
    u16* Xl   = (u16*)p; p += (size_t)B * TE * 2;
    u16* WOth = (u16*)p; p += (size_t)E * HE * 2;   // 14.2 MB (768 x 9216)
    u16* WOtl = (u16*)p; p += (size_t)E * HE * 2;
    u16* Wth  = (u16*)p; p += (size_t)3 * EE * 2;   // 3.5 MB (per-head, reused)
    u16* Wtl  = (u16*)p; p += (size_t)3 * EE * 2;
    u16* zp   = (u16*)p; p += 4096;                 // zero page for window OOB
    size_t used = (size_t)(p - (char*)d_ws);
    size_t slice = (size_t)(8 * TE + 2 * TT) * 2;   // Q,K,V,Z hi/lo + S hi/lo
    int NC = (int)((ws_size - used) / slice);
    if (NC < 1) NC = 1;
    if (NC > B) NC = B;
    u16* Qh = (u16*)p; p += (size_t)NC * TE * 2;
    u16* Ql = (u16*)p; p += (size_t)NC * TE * 2;
    u16* Kh = (u16*)p; p += (size_t)NC * TE * 2;
    u16* Kl = (u16*)p; p += (size_t)NC * TE * 2;
    u16* Vh = (u16*)p; p += (size_t)NC * TE * 2;
    u16* Vl = (u16*)p; p += (size_t)NC * TE * 2;
    u16* Zh = (u16*)p; p += (size_t)NC * TE * 2;
    u16* Zl = (u16*)p; p += (size_t)NC * TE * 2;
    u16* Sh = (u16*)p; p += (size_t)NC * TT * 2;
    u16* Sl = (u16*)p; p += (size_t)NC * TT * 2;

    hipMemsetAsync(out, 0, (size_t)B * TE * sizeof(float), stream);
    hipMemsetAsync(zp, 0, 4096, stream);

    dim3 blk(256);

    // One-time operand splits.
    k_split<<<2048, blk, 0, stream>>>(x, Xh, Xl, (long long)B * TE);
    k_tsplit<<<dim3(E / 32, (int)HE / 32), blk, 0, stream>>>(WO, WOth, WOtl, (int)HE, E);

    for (int h = 0; h < H; ++h) {
        // Quirky-reshape window: out row i reads Zc flat [i*9216,(i+1)*9216);
        // head h owns flat [h*786432,(h+1)*786432). Bounds multiples of 768.
        const int i_lo = (int)(((long long)h * TE) / HE);
        const long long aShift = (long long)i_lo * HE - (long long)h * TE;

        k_tsplit3<<<dim3(24, 24, 3), blk, 0, stream>>>(
            WQ + (size_t)h * EE, WK + (size_t)h * EE, WV + (size_t)h * EE, Wth, Wtl);

        for (int b0 = 0; b0 < B; b0 += NC) {
            const int nb = (B - b0 < NC) ? (B - b0) : NC;

            // Q/K/V projections: (nb*T x 768) @ (768 x 768), B^T staged.
            g_qkv<<<dim3(6, nb * T / 128, 3), blk, 0, stream>>>(
                Xh + (size_t)b0 * TE, Xl + (size_t)b0 * TE, Wth, Wtl,
                Qh, Ql, Kh, Kl, Vh, Vl);

            // Scores: Q (T x 768) @ K-flat reinterpreted (768 x 1024), ldb=T.
            g_km<<<dim3(8, 8, nb), blk, 0, stream>>>(
                Qh, Ql, Kh, Kl, Sh, Sl, 768, 768, 1024, 1024, TE, TE, TT);

            // Softmax over query axis, 1/sqrt(T) pre-scale, in place (hi/lo).
            col_softmax<<<dim3(16, nb), blk, 0, stream>>>(Sh, Sl, 1024, 0.03125f);

            // Z = A (T x T) @ V (T x 768), k-major B.
            g_km<<<dim3(6, 8, nb), blk, 0, stream>>>(
                Sh, Sl, Vh, Vl, Zh, Zl, 1024, 1024, 768, 768, TT, TE, TE);

            // Final projection, windowed A, k-split x24 + atomics.
            g_fin<<<dim3(6, 24, nb), blk, 0, stream>>>(
                Zh, Zl, WOth, WOtl,
                out + (size_t)b0 * TE + (size_t)i_lo * E, zp,
                aShift, T - i_lo, 24);
        }
    }
}

// Round 4
// 4288.946 us; speedup vs baseline: 1.3705x; 1.3705x over previous
//
#include <hip/hip_runtime.h>

// B=8, T=1024, E=768, H=12.
// Round 8: round-7b bf16-split GEMMs kept verbatim; column softmax rebuilt as
// 3-phase high-parallelism streaming kernels (partial m/s -> reduce -> norm),
// u16x4 vectorized, grid ~2048 blocks vs 128. Z aliased onto Q to shrink the
// per-batch workspace slice (13.6 MB) so more batches fit per chunk.

typedef __bf16 bf16x8 __attribute__((ext_vector_type(8)));
typedef float  f32x4  __attribute__((ext_vector_type(4)));
typedef unsigned short u16;
typedef u16 u16x8 __attribute__((ext_vector_type(8)));
typedef u16 u16x4 __attribute__((ext_vector_type(4)));
typedef unsigned int u32;

#define RC 16   // row-chunks for 3-phase softmax

__device__ __forceinline__ float bf2f(u16 u) {
    union { u32 i; float f; } x; x.i = ((u32)u) << 16; return x.f;
}
__device__ __forceinline__ u16 f2bf(float f) {
    __bf16 h = (__bf16)f; union { __bf16 b; u16 u; } x; x.b = h; return x.u;
}
__device__ __forceinline__ void split2(float v, u16& h, u16& l) {
    h = f2bf(v); l = f2bf(v - bf2f(h));
}

__device__ __forceinline__ void gl16(const void* g, void* l) {
    __builtin_amdgcn_global_load_lds(
        (const __attribute__((address_space(1))) u32*)g,
        (__attribute__((address_space(3))) u32*)l, 16, 0, 0);
}

// ---------------- 128x128 split-bf16 core ----------------
// A: hi/lo row-major (M x K, lda).  B: BKMAJ=0 -> B^T hi/lo row-major
// (N x K, ldb) staged via global_load_lds; BKMAJ=1 -> B hi/lo k-major
// (K x N, ldb) staged via coalesced bf16 loads + swizzled ds_write_b128.
// WIN=1: per-lane A-source clamp to zero page for the quirky flat window.
template<int BKMAJ, int WIN>
__device__ __forceinline__ void core(
    const u16* __restrict__ Ah, const u16* __restrict__ Al,
    const u16* __restrict__ Bh, const u16* __restrict__ Bl,
    float* __restrict__ C, u16* __restrict__ Ch, u16* __restrict__ Cl,
    int K, int lda, int ldb, int ldc,
    long long aShift, long long aHi, const u16* __restrict__ zp,
    int mClip, int mode, int mtile, int kChunk, int kChunks, int n0)
{
    __shared__ u16 Ahs[4096], Als[4096], Bhs[4096], Bls[4096]; // 32 KiB

    const int tid = threadIdx.x, lane = tid & 63, w = tid >> 6;
    const int m0 = mtile * 128;
    const int wm = (w & 1) << 6, wn = (w >> 1) << 6;
    const int lr = lane & 15, lq = lane >> 4;
    const int rs = (lr >> 1) & 3;
    const int fro = (lq ^ rs) << 4;            // frag byte offset in row

    // DMA staging geometry: wave w covers LDS rows w*16..+15 (call 0)
    // and +64 (call 1); lane -> (row, 16B slot). Source k pre-swizzled.
    const int srow = (w << 4) + (lane >> 2);
    const int kk = (((lane & 3) ^ ((srow >> 1) & 3)) << 3);
    const int lds0 = (w << 10), lds1 = lds0 + 4096;

    // k-major B staging (scores / Z)
    const int nB = tid & 127, khB = (tid >> 7) << 4;
    const int rsB = (nB >> 1) & 3;
    const int sB0 = (((khB >> 3) ^ rsB) << 4);
    const int sB1 = ((((khB >> 3) | 1) ^ rsB) << 4);

    f32x4 acc[4][4] = {};
    const int kLen = K / kChunks;
    const int kBeg = kChunk * kLen, kEnd = kBeg + kLen;

    u16 rBh[16], rBl[16];
    auto loadB = [&](int k0) {
        if constexpr (BKMAJ) {
#pragma unroll
            for (int j = 0; j < 16; ++j) {
                long long o = (long long)(k0 + khB + j) * ldb + n0 + nB;
                rBh[j] = Bh[o]; rBl[j] = Bl[o];
            }
        }
    };
    auto stage = [&](int k0) {
        long long o1 = (long long)(m0 + srow) * lda + k0 + kk;
        long long o2 = o1 + (long long)64 * lda;
        const u16 *p1h = Ah + o1, *p1l = Al + o1;
        const u16 *p2h = Ah + o2, *p2l = Al + o2;
        if constexpr (WIN) {
            long long a1 = o1 + aShift, a2 = o2 + aShift;
            bool v1 = (a1 >= 0) && (a1 < aHi);
            bool v2 = (a2 >= 0) && (a2 < aHi);
            p1h = v1 ? Ah + a1 : zp;  p1l = v1 ? Al + a1 : zp;
            p2h = v2 ? Ah + a2 : zp;  p2l = v2 ? Al + a2 : zp;
        }
        gl16(p1h, (char*)Ahs + lds0);  gl16(p2h, (char*)Ahs + lds1);
        gl16(p1l, (char*)Als + lds0);  gl16(p2l, (char*)Als + lds1);
        if constexpr (!BKMAJ) {
            long long b1 = (long long)(n0 + srow) * ldb + k0 + kk;
            long long b2 = b1 + (long long)64 * ldb;
            gl16(Bh + b1, (char*)Bhs + lds0);  gl16(Bh + b2, (char*)Bhs + lds1);
            gl16(Bl + b1, (char*)Bls + lds0);  gl16(Bl + b2, (char*)Bls + lds1);
        }
    };
    auto writeB = [&]() {
        if constexpr (BKMAJ) {
            u16x8 h0, h1, l0, l1;
#pragma unroll
            for (int j = 0; j < 8; ++j) {
                h0[j] = rBh[j]; h1[j] = rBh[j + 8];
                l0[j] = rBl[j]; l1[j] = rBl[j + 8];
            }
            *(u16x8*)((char*)Bhs + nB * 64 + sB0) = h0;
            *(u16x8*)((char*)Bhs + nB * 64 + sB1) = h1;
            *(u16x8*)((char*)Bls + nB * 64 + sB0) = l0;
            *(u16x8*)((char*)Bls + nB * 64 + sB1) = l1;
        }
    };

    loadB(kBeg);
    for (int k0 = kBeg; k0 < kEnd; k0 += 32) {
        stage(k0);                       // async DMA into LDS
        writeB();                        // (BKMAJ) prefetched B -> LDS
        __syncthreads();                 // drains vmcnt + lgkmcnt
        if (k0 + 32 < kEnd) loadB(k0 + 32);   // (BKMAJ) prefetch next

        bf16x8 a_h[4], a_l[4];
#pragma unroll
        for (int mi = 0; mi < 4; ++mi) {
            int off = ((wm + (mi << 4) + lr) << 6) + fro;
            a_h[mi] = *(const bf16x8*)((char*)Ahs + off);
            a_l[mi] = *(const bf16x8*)((char*)Als + off);
        }
#pragma unroll
        for (int ni = 0; ni < 4; ++ni) {
            int off = ((wn + (ni << 4) + lr) << 6) + fro;
            bf16x8 b_h = *(const bf16x8*)((char*)Bhs + off);
            bf16x8 b_l = *(const bf16x8*)((char*)Bls + off);
#pragma unroll
            for (int mi = 0; mi < 4; ++mi) {
                acc[mi][ni] = __builtin_amdgcn_mfma_f32_16x16x32_bf16(a_h[mi], b_h, acc[mi][ni], 0, 0, 0);
                acc[mi][ni] = __builtin_amdgcn_mfma_f32_16x16x32_bf16(a_l[mi], b_h, acc[mi][ni], 0, 0, 0);
                acc[mi][ni] = __builtin_amdgcn_mfma_f32_16x16x32_bf16(a_h[mi], b_l, acc[mi][ni], 0, 0, 0);
            }
        }
        __syncthreads();
    }

    // Epilogue: C/D layout col = lane&15, row = (lane>>4)*4 + reg  [m89]
#pragma unroll
    for (int mi = 0; mi < 4; ++mi)
#pragma unroll
        for (int r = 0; r < 4; ++r) {
            int row = m0 + wm + (mi << 4) + (lq << 2) + r;
            if (row < mClip) {
#pragma unroll
                for (int ni = 0; ni < 4; ++ni) {
                    long long off = (long long)row * ldc + n0 + wn + (ni << 4) + lr;
                    float v = acc[mi][ni][r];
                    if (mode == 2)      atomicAdd(&C[off], v);
                    else if (mode == 1) { u16 hh, ll; split2(v, hh, ll); Ch[off] = hh; Cl[off] = ll; }
                    else                C[off] = v;
                }
            }
        }
}

// Fused QKV: grid (6, nbT/128, 3); z selects W-slice and output pair.
__global__ __launch_bounds__(256, 3)
void g_qkv(const u16* __restrict__ Xh, const u16* __restrict__ Xl,
           const u16* __restrict__ Wth, const u16* __restrict__ Wtl,
           u16* __restrict__ Qh, u16* __restrict__ Ql,
           u16* __restrict__ Kh, u16* __restrict__ Kl,
           u16* __restrict__ Vh, u16* __restrict__ Vl)
{
    const long long EE = 768LL * 768;
    int z = blockIdx.z;
    const u16* bh = Wth + (long long)z * EE;
    const u16* bl = Wtl + (long long)z * EE;
    u16* ch = (z == 0) ? Qh : (z == 1) ? Kh : Vh;
    u16* cl = (z == 0) ? Ql : (z == 1) ? Kl : Vl;
    core<0, 0>(Xh, Xl, bh, bl, nullptr, ch, cl, 768, 768, 768, 768,
               0, 0, nullptr, 1 << 30, 1, blockIdx.y, 0, 1, blockIdx.x * 128);
}

// k-major-B GEMM (scores: B = K-flat reinterpreted (768,1024); Z: B = V).
__global__ __launch_bounds__(256, 3)
void g_km(const u16* __restrict__ Ah, const u16* __restrict__ Al,
          const u16* __restrict__ Bh, const u16* __restrict__ Bl,
          u16* __restrict__ Ch, u16* __restrict__ Cl,
          int K, int lda, int ldb, int ldc,
          long long sA, long long sB, long long sC)
{
    long long z = blockIdx.z;
    core<1, 0>(Ah + z * sA, Al + z * sA, Bh + z * sB, Bl + z * sB,
               nullptr, Ch + z * sC, Cl + z * sC,
               K, lda, ldb, ldc, 0, 0, nullptr, 1 << 30, 1,
               blockIdx.y, 0, 1, blockIdx.x * 128);
}

// Final projection: windowed A (quirky flat reshape), k-split + atomics.
__global__ __launch_bounds__(256, 3)
void g_fin(const u16* __restrict__ Zh, const u16* __restrict__ Zl,
           const u16* __restrict__ WOth, const u16* __restrict__ WOtl,
           float* __restrict__ C, const u16* __restrict__ zp,
           long long aShift, int mClip, int kChunks)
{
    const long long TE_ = 786432;
    long long z = blockIdx.z;
    core<0, 1>(Zh + z * TE_, Zl + z * TE_, WOth, WOtl, C + z * TE_,
               nullptr, nullptr, 9216, 9216, 9216, 768,
               aShift, TE_, zp, mClip, 2, 0, blockIdx.y, kChunks, blockIdx.x * 128);
}

// fp32 -> (hi,lo) bf16, flat.
__global__ void k_split(const float* __restrict__ s, u16* __restrict__ h,
                        u16* __restrict__ l, long long n)
{
    long long i = ((long long)blockIdx.x * blockDim.x + threadIdx.x) * 4;
    long long stride = (long long)gridDim.x * blockDim.x * 4;
    for (; i < n; i += stride) {
        float4 v = *(const float4*)(s + i);
        u16x4 hh, ll;
        u16 h0, l0, h1, l1, h2, l2, h3, l3;
        split2(v.x, h0, l0); split2(v.y, h1, l1);
        split2(v.z, h2, l2); split2(v.w, h3, l3);
        hh[0] = h0; hh[1] = h1; hh[2] = h2; hh[3] = h3;
        ll[0] = l0; ll[1] = l1; ll[2] = l2; ll[3] = l3;
        *(u16x4*)(h + i) = hh;
        *(u16x4*)(l + i) = ll;
    }
}

// fp32 (Ks x Ns) -> transposed (Ns x Ks) hi/lo bf16.
__global__ void k_tsplit(const float* __restrict__ s, u16* __restrict__ dh,
                         u16* __restrict__ dl, int Ks, int Ns)
{
    __shared__ float t[32][33];
    int tx = threadIdx.x & 31, ty = threadIdx.x >> 5;
    int kb = blockIdx.y << 5, nb_ = blockIdx.x << 5;
#pragma unroll
    for (int i = 0; i < 4; ++i)
        t[ty + 8 * i][tx] = s[(long long)(kb + ty + 8 * i) * Ns + nb_ + tx];
    __syncthreads();
#pragma unroll
    for (int i = 0; i < 4; ++i) {
        float v = t[tx][ty + 8 * i];
        long long o = (long long)(nb_ + ty + 8 * i) * Ks + kb + tx;
        u16 hh, ll; split2(v, hh, ll);
        dh[o] = hh; dl[o] = ll;
    }
}

// Per-head W transpose-split: z selects WQ/WK/WV slice; dst += z*E*E.
__global__ void k_tsplit3(const float* __restrict__ s0, const float* __restrict__ s1,
                          const float* __restrict__ s2,
                          u16* __restrict__ dh, u16* __restrict__ dl)
{
    const int E = 768; const long long EE = (long long)E * E;
    const float* s = (blockIdx.z == 0) ? s0 : (blockIdx.z == 1) ? s1 : s2;
    u16* h = dh + blockIdx.z * EE;
    u16* l = dl + blockIdx.z * EE;
    __shared__ float t[32][33];
    int tx = threadIdx.x & 31, ty = threadIdx.x >> 5;
    int kb = blockIdx.y << 5, nb_ = blockIdx.x << 5;
#pragma unroll
    for (int i = 0; i < 4; ++i)
        t[ty + 8 * i][tx] = s[(long long)(kb + ty + 8 * i) * E + nb_ + tx];
    __syncthreads();
#pragma unroll
    for (int i = 0; i < 4; ++i) {
        float v = t[tx][ty + 8 * i];
        long long o = (long long)(nb_ + ty + 8 * i) * E + kb + tx;
        u16 hh, ll; split2(v, hh, ll);
        h[o] = hh; l[o] = ll;
    }
}

// ---------------- 3-phase column softmax (query-axis) ----------------
// Phase A: per-(column, row-chunk) partial (max, sum). grid (T/256, RC, nb);
// block 256 = 4 row-segs x 64 lanes; lane owns 4 consecutive columns (u16x4).
__global__ __launch_bounds__(256)
void sm_part(const u16* __restrict__ Sh, const u16* __restrict__ Sl,
             float2* __restrict__ part, int T, float scale)
{
    const int lane = threadIdx.x & 63, seg = threadIdx.x >> 6;
    const int j0 = blockIdx.x * 256 + lane * 4;
    const long long base = (long long)blockIdx.z * T * T;
    const int rpc = T / RC, rps = rpc / 4;
    const int r0 = blockIdx.y * rpc + seg * rps;

    float m[4] = {-3.4e38f, -3.4e38f, -3.4e38f, -3.4e38f};
    float s[4] = {0.f, 0.f, 0.f, 0.f};
    for (int r = 0; r < rps; ++r) {
        long long o = base + (long long)(r0 + r) * T + j0;
        u16x4 vh = *(const u16x4*)(Sh + o);
        u16x4 vl = *(const u16x4*)(Sl + o);
#pragma unroll
        for (int c = 0; c < 4; ++c) {
            float v = (bf2f(vh[c]) + bf2f(vl[c])) * scale;
            float mn = fmaxf(m[c], v);
            s[c] = s[c] * __expf(m[c] - mn) + __expf(v - mn);
            m[c] = mn;
        }
    }
    __shared__ float4 smm[4][64], sss[4][64];
    smm[seg][lane] = make_float4(m[0], m[1], m[2], m[3]);
    sss[seg][lane] = make_float4(s[0], s[1], s[2], s[3]);
    __syncthreads();
    if (seg == 0) {
#pragma unroll
        for (int q = 1; q < 4; ++q) {
            float4 mq4 = smm[q][lane], sq4 = sss[q][lane];
            float mq[4] = {mq4.x, mq4.y, mq4.z, mq4.w};
            float sq[4] = {sq4.x, sq4.y, sq4.z, sq4.w};
#pragma unroll
            for (int c = 0; c < 4; ++c) {
                float mn = fmaxf(m[c], mq[c]);
                s[c] = s[c] * __expf(m[c] - mn) + sq[c] * __expf(mq[c] - mn);
                m[c] = mn;
            }
        }
        long long pb = ((long long)blockIdx.z * RC + blockIdx.y) * T + j0;
#pragma unroll
        for (int c = 0; c < 4; ++c)
            part[pb + c] = make_float2(m[c], s[c]);
    }
}

// Phase B: reduce RC partials -> per-column (max, 1/sum). grid (T/256, nb).
__global__ __launch_bounds__(256)
void sm_fin2(const float2* __restrict__ part, float2* __restrict__ fin, int T)
{
    int j = blockIdx.x * 256 + threadIdx.x;
    long long pb = (long long)blockIdx.y * RC * T + j;
    float mt = -3.4e38f, st = 0.f;
#pragma unroll
    for (int q = 0; q < RC; ++q) {
        float2 p = part[pb + (long long)q * T];
        float mn = fmaxf(mt, p.x);
        st = st * __expf(mt - mn) + p.y * __expf(p.x - mn);
        mt = mn;
    }
    fin[(long long)blockIdx.y * T + j] = make_float2(mt, 1.f / st);
}

// Phase C: normalize in place. Same geometry as phase A.
__global__ __launch_bounds__(256)
void sm_norm(u16* __restrict__ Sh, u16* __restrict__ Sl,
             const float2* __restrict__ fin, int T, float scale)
{
    const int lane = threadIdx.x & 63, seg = threadIdx.x >> 6;
    const int j0 = blockIdx.x * 256 + lane * 4;
    const long long base = (long long)blockIdx.z * T * T;
    const int rpc = T / RC, rps = rpc / 4;
    const int r0 = blockIdx.y * rpc + seg * rps;
    float mt[4], inv[4];
#pragma unroll
    for (int c = 0; c < 4; ++c) {
        float2 f = fin[(long long)blockIdx.z * T + j0 + c];
        mt[c] = f.x; inv[c] = f.y;
    }
    for (int r = 0; r < rps; ++r) {
        long long o = base + (long long)(r0 + r) * T + j0;
        u16x4 vh = *(const u16x4*)(Sh + o);
        u16x4 vl = *(const u16x4*)(Sl + o);
        u16x4 oh, ol;
#pragma unroll
        for (int c = 0; c < 4; ++c) {
            float v = (bf2f(vh[c]) + bf2f(vl[c])) * scale;
            float p = __expf(v - mt[c]) * inv[c];
            u16 hh, ll; split2(p, hh, ll);
            oh[c] = hh; ol[c] = ll;
        }
        *(u16x4*)(Sh + o) = oh;
        *(u16x4*)(Sl + o) = ol;
    }
}

extern "C" void kernel_launch(void* const* d_in, const int* in_sizes, int n_in,
                              void* d_out, int out_size, void* d_ws, size_t ws_size,
                              hipStream_t stream)
{
    const float* x  = (const float*)d_in[0];   // (B,T,E)
    const float* WQ = (const float*)d_in[1];   // (H,E,E)
    const float* WK = (const float*)d_in[2];
    const float* WV = (const float*)d_in[3];
    const float* WO = (const float*)d_in[4];   // (H*E, E)
    float* out = (float*)d_out;                // (B,T,E)

    const int B = 8, T = 1024, E = 768, H = 12;
    const long long TE = (long long)T * E;     // 786432
    const long long TT = (long long)T * T;     // 1048576
    const long long HE = (long long)H * E;     // 9216
    const long long EE = (long long)E * E;

    // ---- workspace layout (bytes) ----
    char* p = (char*)d_ws;
    u16* Xh   = (u16*)p; p += (size_t)B * TE * 2;   // 12.6 MB
    u16* Xl   = (u16*)p; p += (size_t)B * TE * 2;
    u16* WOth = (u16*)p; p += (size_t)E * HE * 2;   // 14.2 MB (768 x 9216)
    u16* WOtl = (u16*)p; p += (size_t)E * HE * 2;
    u16* Wth  = (u16*)p; p += (size_t)3 * EE * 2;   // 3.5 MB (per-head, reused)
    u16* Wtl  = (u16*)p; p += (size_t)3 * EE * 2;
    u16* zp   = (u16*)p; p += 4096;                 // zero page for window OOB
    float2* part = (float2*)p; p += (size_t)B * RC * T * sizeof(float2); // 1 MB
    float2* finb = (float2*)p; p += (size_t)B * T * sizeof(float2);      // 64 KB
    size_t used = (size_t)(p - (char*)d_ws);
    // Slice: Q(=Z),K,V hi/lo + S hi/lo.  Z aliases Q (Q dead after scores).
    size_t slice = (size_t)(6 * TE + 2 * TT) * 2;   // 13.6 MB
    int NC = (int)((ws_size - used) / slice);
    if (NC < 1) NC = 1;
    if (NC > B) NC = B;
    u16* Qh = (u16*)p; p += (size_t)NC * TE * 2;
    u16* Ql = (u16*)p; p += (size_t)NC * TE * 2;
    u16* Kh = (u16*)p; p += (size_t)NC * TE * 2;
    u16* Kl = (u16*)p; p += (size_t)NC * TE * 2;
    u16* Vh = (u16*)p; p += (size_t)NC * TE * 2;
    u16* Vl = (u16*)p; p += (size_t)NC * TE * 2;
    u16* Sh = (u16*)p; p += (size_t)NC * TT * 2;
    u16* Sl = (u16*)p; p += (size_t)NC * TT * 2;
    u16* Zh = Qh;   // alias: Q dead after scores GEMM
    u16* Zl = Ql;

    hipMemsetAsync(out, 0, (size_t)B * TE * sizeof(float), stream);
    hipMemsetAsync(zp, 0, 4096, stream);

    dim3 blk(256);

    // One-time operand splits.
    k_split<<<2048, blk, 0, stream>>>(x, Xh, Xl, (long long)B * TE);
    k_tsplit<<<dim3(E / 32, (int)HE / 32), blk, 0, stream>>>(WO, WOth, WOtl, (int)HE, E);

    for (int h = 0; h < H; ++h) {
        // Quirky-reshape window: out row i reads Zc flat [i*9216,(i+1)*9216);
        // head h owns flat [h*786432,(h+1)*786432). Bounds multiples of 768.
        const int i_lo = (int)(((long long)h * TE) / HE);
        const long long aShift = (long long)i_lo * HE - (long long)h * TE;

        k_tsplit3<<<dim3(24, 24, 3), blk, 0, stream>>>(
            WQ + (size_t)h * EE, WK + (size_t)h * EE, WV + (size_t)h * EE, Wth, Wtl);

        for (int b0 = 0; b0 < B; b0 += NC) {
            const int nb = (B - b0 < NC) ? (B - b0) : NC;

            // Q/K/V projections: (nb*T x 768) @ (768 x 768), B^T staged.
            g_qkv<<<dim3(6, nb * T / 128, 3), blk, 0, stream>>>(
                Xh + (size_t)b0 * TE, Xl + (size_t)b0 * TE, Wth, Wtl,
                Qh, Ql, Kh, Kl, Vh, Vl);

            // Scores: Q (T x 768) @ K-flat reinterpreted (768 x 1024), ldb=T.
            g_km<<<dim3(8, 8, nb), blk, 0, stream>>>(
                Qh, Ql, Kh, Kl, Sh, Sl, 768, 768, 1024, 1024, TE, TE, TT);

            // Softmax over query axis, 1/sqrt(T) pre-scale, 3-phase.
            sm_part<<<dim3(T / 256, RC, nb), blk, 0, stream>>>(Sh, Sl, part, T, 0.03125f);
            sm_fin2<<<dim3(T / 256, nb), blk, 0, stream>>>(part, finb, T);
            sm_norm<<<dim3(T / 256, RC, nb), blk, 0, stream>>>(Sh, Sl, finb, T, 0.03125f);

            // Z = A (T x T) @ V (T x 768), k-major B.  (Z aliases Q.)
            g_km<<<dim3(6, 8, nb), blk, 0, stream>>>(
                Sh, Sl, Vh, Vl, Zh, Zl, 1024, 1024, 768, 768, TT, TE, TE);

            // Final projection, windowed A, k-split x24 + atomics.
            g_fin<<<dim3(6, 24, nb), blk, 0, stream>>>(
                Zh, Zl, WOth, WOtl,
                out + (size_t)b0 * TE + (size_t)i_lo * E, zp,
                aShift, T - i_lo, 24);
        }
    }
}